// Round 2
// baseline (397.517 us; speedup 1.0000x reference)
//
#include <hip/hip_runtime.h>

#define WIRE_DIM  32
#define NUM_WIRES 64
#define BATCH     8192
#define HID       10
#define NB        2          // batches per wave

// broadcast-read a float from a wave-uniform lane index (SGPR) -> SGPR result
__device__ __forceinline__ float rl(float x, int slane) {
    return __uint_as_float(__builtin_amdgcn_readlane(__float_as_uint(x), slane));
}

__global__ __launch_bounds__(256, 4) void isnet_kernel(
    const float* __restrict__ outputs,
    const int*   __restrict__ tests,
    const float* __restrict__ W1,
    const float* __restrict__ b1,
    const float* __restrict__ W2,
    const float* __restrict__ b2,
    float*       __restrict__ out)
{
    // W1 transposed: sW1t[h*64 + d] = W1[d*10 + h] -> per-h contiguous float4,
    // wave-uniform address => ds_read_b128 broadcast, zero bank conflicts
    __shared__ __align__(16) float sW1t[HID * 64];
    __shared__ float sB1[HID], sW2[HID], sB2;

    const int tid  = threadIdx.x;
    const int lane = tid & 63;
    const int wave = tid >> 6;

    for (int i = tid; i < 64 * HID; i += 256) {
        int d = i / HID, h = i - d * HID;
        sW1t[h * 64 + d] = W1[i];
    }
    if (tid < HID) { sB1[tid] = b1[tid]; sW2[tid] = W2[tid]; }
    if (tid == 0)  sB2 = b2[0];
    __syncthreads();

    const int b0 = blockIdx.x * (4 * NB) + wave * NB;

    // person / location are wave-uniform per batch -> SGPRs
    int sp[NB], sl[NB];
    #pragma unroll
    for (int nb = 0; nb < NB; ++nb) {
        sp[nb] = __builtin_amdgcn_readfirstlane(tests[2 * (b0 + nb)]);
        sl[nb] = __builtin_amdgcn_readfirstlane(tests[2 * (b0 + nb) + 1]);
    }

    // the ONLY HBM stream: each lane loads its own wire row (lane == wire)
    float4 w[NB][8];
    #pragma unroll
    for (int nb = 0; nb < NB; ++nb) {
        const float* row = outputs + (size_t)(b0 + nb) * (NUM_WIRES * WIRE_DIM)
                         + lane * WIRE_DIM;
        #pragma unroll
        for (int j = 0; j < 8; ++j) w[nb][j] = *(const float4*)(row + 4 * j);
    }

    float acc[NB][HID];
    #pragma unroll
    for (int nb = 0; nb < NB; ++nb)
        #pragma unroll
        for (int h = 0; h < HID; ++h) acc[nb][h] = sB1[h];

    // person half (W1 rows 0..31): person_vec[d] = readlane(wire[d], person)
    #pragma unroll
    for (int j = 0; j < 8; ++j) {
        float px[NB], py[NB], pz[NB], pw[NB];
        #pragma unroll
        for (int nb = 0; nb < NB; ++nb) {
            px[nb] = rl(w[nb][j].x, sp[nb]);
            py[nb] = rl(w[nb][j].y, sp[nb]);
            pz[nb] = rl(w[nb][j].z, sp[nb]);
            pw[nb] = rl(w[nb][j].w, sp[nb]);
        }
        #pragma unroll
        for (int h = 0; h < HID; ++h) {
            float4 wt = *(const float4*)&sW1t[h * 64 + 4 * j];
            #pragma unroll
            for (int nb = 0; nb < NB; ++nb)
                acc[nb][h] += px[nb] * wt.x + py[nb] * wt.y
                            + pz[nb] * wt.z + pw[nb] * wt.w;
        }
    }
    // wire half (W1 rows 32..63): per-lane data already in registers
    #pragma unroll
    for (int j = 0; j < 8; ++j) {
        #pragma unroll
        for (int h = 0; h < HID; ++h) {
            float4 wt = *(const float4*)&sW1t[h * 64 + 32 + 4 * j];
            #pragma unroll
            for (int nb = 0; nb < NB; ++nb)
                acc[nb][h] += w[nb][j].x * wt.x + w[nb][j].y * wt.y
                            + w[nb][j].z * wt.z + w[nb][j].w * wt.w;
        }
    }

    // relu -> W2 -> logit per lane(=wire) -> wave softmax -> loss
    #pragma unroll
    for (int nb = 0; nb < NB; ++nb) {
        float v = sB2;
        #pragma unroll
        for (int h = 0; h < HID; ++h) v += fmaxf(acc[nb][h], 0.f) * sW2[h];

        float m = v;
        #pragma unroll
        for (int off = 32; off > 0; off >>= 1) m = fmaxf(m, __shfl_xor(m, off));
        float e = __expf(v - m);
        float s = e;
        #pragma unroll
        for (int off = 32; off > 0; off >>= 1) s += __shfl_xor(s, off);
        float lv = rl(v, sl[nb]);                       // logit at `location`
        if (lane == 0) out[b0 + nb] = m + __logf(s) - lv;  // -log_softmax[loc]
    }
}

extern "C" void kernel_launch(void* const* d_in, const int* in_sizes, int n_in,
                              void* d_out, int out_size, void* d_ws, size_t ws_size,
                              hipStream_t stream) {
    const float* outputs = (const float*)d_in[0];
    const int*   tests   = (const int*)d_in[1];
    const float* W1      = (const float*)d_in[2];
    const float* b1      = (const float*)d_in[3];
    const float* W2      = (const float*)d_in[4];
    const float* b2      = (const float*)d_in[5];
    float* out = (float*)d_out;

    // 8 batches per block (4 waves x NB=2) -> 1024 blocks = 4 blocks/CU,
    // whole problem resident in one generation at 4 waves/SIMD
    isnet_kernel<<<BATCH / (4 * NB), 256, 0, stream>>>(
        outputs, tests, W1, b1, W2, b2, out);
}

// Round 3
// 109.980 us; speedup vs baseline: 3.6144x; 3.6144x over previous
//
#include <hip/hip_runtime.h>

#define WIRE_DIM  32
#define NUM_WIRES 64
#define BATCH     8192
#define HID       10

// broadcast-read a float from a wave-uniform lane index -> scalar
__device__ __forceinline__ float rl(float x, int slane) {
    return __uint_as_float(__builtin_amdgcn_readlane(__float_as_uint(x), slane));
}

__global__ __launch_bounds__(256) void isnet_kernel(
    const float* __restrict__ outputs,
    const int*   __restrict__ tests,
    const float* __restrict__ W1,
    const float* __restrict__ b1,
    const float* __restrict__ W2,
    const float* __restrict__ b2,
    float*       __restrict__ out)
{
    // W1 transposed: sW1t[h*64 + d] = W1[d*10 + h] -> per-h contiguous float4,
    // wave-uniform address => ds_read_b128 broadcast, zero bank conflicts
    __shared__ __align__(16) float sW1t[HID * 64];
    __shared__ float sB1[HID], sW2[HID], sB2;

    const int tid  = threadIdx.x;
    const int lane = tid & 63;
    const int wave = tid >> 6;

    for (int i = tid; i < 64 * HID; i += 256) {
        int d = i / HID, h = i - d * HID;
        sW1t[h * 64 + d] = W1[i];
    }
    if (tid < HID) { sB1[tid] = b1[tid]; sW2[tid] = W2[tid]; }
    if (tid == 0)  sB2 = b2[0];
    __syncthreads();

    // one batch per wave (NB=1): register pressure ~70 VGPR, no spill by design
    const int b = blockIdx.x * 4 + wave;

    const int sp = __builtin_amdgcn_readfirstlane(tests[2 * b]);      // person
    const int sl = __builtin_amdgcn_readfirstlane(tests[2 * b + 1]);  // location

    // the ONLY HBM stream: each lane loads its own wire row (lane == wire),
    // 8 x float4 issued back-to-back (32 VGPRs of destinations)
    const float* row = outputs + (size_t)b * (NUM_WIRES * WIRE_DIM) + lane * WIRE_DIM;
    float4 w[8];
    #pragma unroll
    for (int j = 0; j < 8; ++j) w[j] = *(const float4*)(row + 4 * j);

    float acc[HID];
    #pragma unroll
    for (int h = 0; h < HID; ++h) acc[h] = sB1[h];

    #pragma unroll
    for (int j = 0; j < 8; ++j) {
        // person vector chunk: broadcast from the lane that owns it
        const float px = rl(w[j].x, sp);
        const float py = rl(w[j].y, sp);
        const float pz = rl(w[j].z, sp);
        const float pw = rl(w[j].w, sp);
        #pragma unroll
        for (int h = 0; h < HID; ++h) {
            // person half: W1 rows 4j..4j+3
            float4 wa = *(const float4*)&sW1t[h * 64 + 4 * j];
            // wire half: W1 rows 32+4j..32+4j+3
            float4 wb = *(const float4*)&sW1t[h * 64 + 32 + 4 * j];
            acc[h] += px * wa.x + py * wa.y + pz * wa.z + pw * wa.w
                    + w[j].x * wb.x + w[j].y * wb.y
                    + w[j].z * wb.z + w[j].w * wb.w;
        }
    }

    // relu -> W2 -> logit per lane(=wire)
    float v = sB2;
    #pragma unroll
    for (int h = 0; h < HID; ++h) v += fmaxf(acc[h], 0.f) * sW2[h];

    // wave softmax over the 64 wires
    float m = v;
    #pragma unroll
    for (int off = 32; off > 0; off >>= 1) m = fmaxf(m, __shfl_xor(m, off));
    float e = __expf(v - m);
    float s = e;
    #pragma unroll
    for (int off = 32; off > 0; off >>= 1) s += __shfl_xor(s, off);
    float lv = rl(v, sl);                        // logit at `location`
    if (lane == 0) out[b] = m + __logf(s) - lv;  // -log_softmax[loc]
}

extern "C" void kernel_launch(void* const* d_in, const int* in_sizes, int n_in,
                              void* d_out, int out_size, void* d_ws, size_t ws_size,
                              hipStream_t stream) {
    const float* outputs = (const float*)d_in[0];
    const int*   tests   = (const int*)d_in[1];
    const float* W1      = (const float*)d_in[2];
    const float* b1      = (const float*)d_in[3];
    const float* W2      = (const float*)d_in[4];
    const float* b2      = (const float*)d_in[5];
    float* out = (float*)d_out;

    // 4 batches per block (4 waves x 1 batch) -> 2048 blocks
    isnet_kernel<<<BATCH / 4, 256, 0, stream>>>(
        outputs, tests, W1, b1, W2, b2, out);
}